// Round 9
// baseline (185.500 us; speedup 1.0000x reference)
//
#include <hip/hip_runtime.h>
#include <hip/hip_bf16.h>

// NT-Xent loss, 2B=8192, D=128, T=0.5. TWO dispatches, NO device fences:
//  k_prep : row-normalize -> bf16 nb; picked logit per row (fp32); zero
//           l_arr and the completion counter.
//  k_gemm : SYMMETRIC Gram, upper-triangle 128x128 tiles via circulant
//           pairing bj=(bi+by)&63, by in [0,32]. Block (bi,g) handles TWO
//           strips {g, g+17}; A fragments loaded once.
//           v9 = v5's half-tile ping-pong pipeline WITHOUT v5's bug:
//           v5 passed correctness but its lambda-by-ref accumulators
//           spilled to scratch (VGPR=64, WRITE 46MB, 134us). v9 uses
//           straight-line MACROS, kernel-scope acc arrays (static idx),
//           and v7's immediate-consumption col atomics (zero carried
//           state). Schedule per block: 4 phases {counted-vmcnt wait ->
//           raw barrier -> MFMA half -> barrier -> stage next half ->
//           exp epilogue + 4 UNIFORM atomics}. Waits 4/8/12/8 derived
//           per-wave (4 gl_lds/stage, 4 atomics/epilogue, uniform via
//           diag cs=0 trick); no vmcnt(0) drain mid-pipeline. 2x16KB
//           LDS -> 4 blocks/CU (= v7 occupancy) AND stage latency hidden
//           under compute. k_final folded (v5/v6-verified): counter +
//           threadfence, last block reduces into out.
//           Fixed softmax max = 2.0 (cos<=1).

typedef __bf16 bf16x8 __attribute__((ext_vector_type(8)));
typedef float floatx4 __attribute__((ext_vector_type(4)));

#define TWO_B 8192
#define B_HALF 4096
#define D 128
#define INV_T 2.0f                 // 1/temperature
#define FIXED_MAX 2.0f             // logit upper bound (cos<=1)
#define C_EXP 2.885390081777927f   // INV_T * log2(e) == FIXED_MAX * log2(e)
#define NBLK (64 * 17)

#if defined(__has_builtin) && __has_builtin(__builtin_amdgcn_exp2f)
#define EXP2F(x) __builtin_amdgcn_exp2f(x)   // raw v_exp_f32; arg in [-5.8, 0]
#else
#define EXP2F(x) exp2f(x)
#endif
#if defined(__has_builtin) && __has_builtin(__builtin_amdgcn_logf)
#define LOG2F(x) __builtin_amdgcn_logf(x)    // raw v_log_f32 (log2)
#else
#define LOG2F(x) log2f(x)
#endif

__device__ inline void load16_lds(const __bf16* g, __bf16* l) {
    __builtin_amdgcn_global_load_lds(
        (const __attribute__((address_space(1))) unsigned int*)g,
        (__attribute__((address_space(3))) unsigned int*)l, 16, 0, 0);
}

// -------- kernel 1: normalize + picked + zero l_arr & counter ------------
__global__ void k_prep(const float* __restrict__ emb,
                       const int* __restrict__ labels,
                       __bf16* __restrict__ nb,
                       float* __restrict__ picked,
                       float* __restrict__ l_arr,
                       unsigned int* __restrict__ cnt) {
    int wv   = threadIdx.x >> 6;
    int lane = threadIdx.x & 63;
    int i = blockIdx.x * 4 + wv;
    const float2* e2 = reinterpret_cast<const float2*>(emb + (size_t)i * D);
    float2 v = e2[lane];
    float ssi = v.x * v.x + v.y * v.y;
    // picked column: labels[i] skips cols {i, i^4096}
    int p = i ^ B_HALF;
    int a = min(i, p), b = max(i, p);
    int l = labels[i];
    int c = l + (l >= a);
    c += (c >= b);
    const float2* ec2 = reinterpret_cast<const float2*>(emb + (size_t)c * D);
    float2 u = ec2[lane];
    float dot = v.x * u.x + v.y * u.y;
    float ssc = u.x * u.x + u.y * u.y;
#pragma unroll
    for (int off = 32; off >= 1; off >>= 1) {
        ssi += __shfl_xor(ssi, off, 64);
        dot += __shfl_xor(dot, off, 64);
        ssc += __shfl_xor(ssc, off, 64);
    }
    float rn = rsqrtf(fmaxf(ssi, 1e-16f));
    union { __bf16 h[2]; unsigned int uu; } pk;
    pk.h[0] = (__bf16)(v.x * rn);
    pk.h[1] = (__bf16)(v.y * rn);
    reinterpret_cast<unsigned int*>(nb)[i * 64 + lane] = pk.uu;
    if (lane == 0)
        picked[i] = dot / fmaxf(sqrtf(ssi * ssc), 1e-8f) * INV_T;
    if (blockIdx.x < TWO_B / 256) l_arr[blockIdx.x * 256 + threadIdx.x] = 0.f;
    if (blockIdx.x == 0 && threadIdx.x == 0) *cnt = 0u;
}

// stage one 64-col x 128-K half tile (16 KB): 4 gl_lds per wave.
// LDS elem j*2048 + w*512 + lane*8+e <-> nb[(BJ*128+H*64+16j+m)*D + w*32+quad*8+e]
#define STAGE_HALF(BJ, H, BUF)                                                \
    do {                                                                      \
        const __bf16* gp_ = nb + (size_t)((BJ) * 128 + (H) * 64 + m) * D      \
                               + w * 32 + quad * 8;                           \
        _Pragma("unroll")                                                     \
        for (int j = 0; j < 4; ++j)                                           \
            load16_lds(gp_ + (size_t)j * 16 * D, &(BUF)[j * 2048 + w * 512]); \
    } while (0)

// 4 sub-tiles x K=128: 8 independent MFMA chains into acc0/acc1
#define COMPUTE_HALF(BUF)                                                     \
    do {                                                                      \
        _Pragma("unroll")                                                     \
        for (int s = 0; s < 4; ++s) {                                         \
            acc0[s] = (floatx4){0.f, 0.f, 0.f, 0.f};                          \
            acc1[s] = (floatx4){0.f, 0.f, 0.f, 0.f};                          \
        }                                                                     \
        _Pragma("unroll")                                                     \
        for (int kc = 0; kc < 4; ++kc) {                                      \
            const bf16x8 a0k = a0[kc], a1k = a1[kc];                          \
            _Pragma("unroll")                                                 \
            for (int s = 0; s < 4; ++s) {                                     \
                bf16x8 b = *reinterpret_cast<const bf16x8*>(                  \
                    &(BUF)[(s * 4 + kc) * 512 + lane * 8]);                   \
                acc0[s] = __builtin_amdgcn_mfma_f32_16x16x32_bf16(a0k, b, acc0[s], 0, 0, 0); \
                acc1[s] = __builtin_amdgcn_mfma_f32_16x16x32_bf16(a1k, b, acc1[s], 0, 0, 0); \
            }                                                                 \
        }                                                                     \
    } while (0)

// epilogue: exp, row/col accumulate; ALWAYS exactly 4 atomic instrs per
// wave (diag zeroes cs but still adds) so vmcnt counts are path-uniform.
#define EPI_HALF(C0H, BMASK, ISDIAG)                                          \
    do {                                                                      \
        _Pragma("unroll")                                                     \
        for (int s = 0; s < 4; ++s) {                                         \
            const int jj = (C0H) + s * 16 + m;                                \
            float cs = 0.f;                                                   \
            if (BMASK) {                                                      \
                _Pragma("unroll")                                             \
                for (int r = 0; r < 4; ++r) {                                 \
                    float e0 = EXP2F(fmaf(acc0[s][r], C_EXP, -C_EXP));        \
                    float e1 = EXP2F(fmaf(acc1[s][r], C_EXP, -C_EXP));        \
                    if (((jj ^ (i0 + r)) & ~B_HALF) == 0) e0 = 0.f;           \
                    if (((jj ^ (i0 + 16 + r)) & ~B_HALF) == 0) e1 = 0.f;      \
                    l0[r] += e0;                                              \
                    l1[r] += e1;                                              \
                    cs += e0 + e1;                                            \
                }                                                             \
            } else {                                                          \
                _Pragma("unroll")                                             \
                for (int r = 0; r < 4; ++r) {                                 \
                    float e0 = EXP2F(fmaf(acc0[s][r], C_EXP, -C_EXP));        \
                    float e1 = EXP2F(fmaf(acc1[s][r], C_EXP, -C_EXP));        \
                    l0[r] += e0;                                              \
                    l1[r] += e1;                                              \
                    cs += e0 + e1;                                            \
                }                                                             \
            }                                                                 \
            cs += __shfl_xor(cs, 16, 64);                                     \
            cs += __shfl_xor(cs, 32, 64);                                     \
            if (ISDIAG) cs = 0.f;                                             \
            if (quad == 0) atomicAdd(&l_arr[jj], cs);                         \
        }                                                                     \
    } while (0)

// -------- kernel 2: symmetric Gram MFMA + masked exp-sum + final ---------
// grid (64, 17), block 256 = 4 waves.
__global__ __launch_bounds__(256, 4) void k_gemm(const __bf16* __restrict__ nb,
                                                 float* __restrict__ l_arr,
                                                 const float* __restrict__ picked,
                                                 float* __restrict__ out,
                                                 unsigned int* __restrict__ cnt) {
    __shared__ __bf16 lds0[8192];            // 16 KB ping
    __shared__ __bf16 lds1[8192];            // 16 KB pong
    __shared__ unsigned int last_flag;
    __shared__ float fred[4];

    const int bi = blockIdx.x;
    const int g  = blockIdx.y;

    const int lane = threadIdx.x & 63;
    const int w    = threadIdx.x >> 6;
    const int m    = lane & 15;
    const int quad = lane >> 4;
    const int row0 = bi * 128 + w * 32;      // wave rows: row0..row0+31

    const int  bj0    = (bi + g) & 63;
    const bool diag0  = (g == 0);
    const bool has1   = (g < 15) || (g == 15 && bi < 32);
    const int  bj1    = (bi + g + 17) & 63;
    const bool bmask1 = (g == 15);           // by==32 partner-pair masking

    // A fragments: issued FIRST; stages issued right after so the A-pin's
    // compiler wait allows the 8 stage loads to stay outstanding.
    bf16x8 a0[4], a1[4];
#pragma unroll
    for (int kc = 0; kc < 4; ++kc) {
        a0[kc] = *reinterpret_cast<const bf16x8*>(
            nb + (size_t)(row0 + m) * D + kc * 32 + quad * 8);
        a1[kc] = *reinterpret_cast<const bf16x8*>(
            nb + (size_t)(row0 + 16 + m) * D + kc * 32 + quad * 8);
    }
    STAGE_HALF(bj0, 0, lds0);                // H0 -> buf0
    STAGE_HALF(bj0, 1, lds1);                // H1 -> buf1
    __builtin_amdgcn_sched_barrier(0);
    asm volatile("" : "+v"(a0[0]), "+v"(a0[1]), "+v"(a0[2]), "+v"(a0[3]),
                      "+v"(a1[0]), "+v"(a1[1]), "+v"(a1[2]), "+v"(a1[3]));
    __builtin_amdgcn_sched_barrier(0);

    float l0[4] = {0.f, 0.f, 0.f, 0.f};      // row sums, carried across strips
    float l1[4] = {0.f, 0.f, 0.f, 0.f};
    const int i0 = row0 + quad * 4;          // l0 rows; l1 rows = i0+16

    floatx4 acc0[4], acc1[4];                // kernel-scope, static indices

    if (has1) {
        // ---- p0: H0/buf0. outstanding newer: H1(4) ----------------------
        asm volatile("s_waitcnt vmcnt(4)" ::: "memory");
        __builtin_amdgcn_s_barrier();
        __builtin_amdgcn_sched_barrier(0);
        COMPUTE_HALF(lds0);
        __builtin_amdgcn_sched_barrier(0);
        __builtin_amdgcn_s_barrier();        // all waves done reading buf0
        STAGE_HALF(bj1, 0, lds0);            // S2
        __builtin_amdgcn_sched_barrier(0);   // atomics stay AFTER stage
        EPI_HALF(bj0 * 128, diag0, diag0);   // E0: 4 atomics
        // ---- p1: H1/buf1. newer: S2(4) + E0(4) --------------------------
        asm volatile("s_waitcnt vmcnt(8)" ::: "memory");
        __builtin_amdgcn_s_barrier();
        __builtin_amdgcn_sched_barrier(0);
        COMPUTE_HALF(lds1);
        __builtin_amdgcn_sched_barrier(0);
        __builtin_amdgcn_s_barrier();        // all waves done reading buf1
        STAGE_HALF(bj1, 1, lds1);            // S3
        __builtin_amdgcn_sched_barrier(0);
        EPI_HALF(bj0 * 128 + 64, diag0, diag0);  // E1
        // ---- p2: H2/buf0. newer: E0(4)+S3(4)+E1(4) ----------------------
        asm volatile("s_waitcnt vmcnt(12)" ::: "memory");
        __builtin_amdgcn_s_barrier();
        __builtin_amdgcn_sched_barrier(0);
        COMPUTE_HALF(lds0);
        __builtin_amdgcn_sched_barrier(0);
        EPI_HALF(bj1 * 128, bmask1, false);  // E2
        // ---- p3: H3/buf1. need S3: retire E0+S3 -> vmcnt(8) -------------
        asm volatile("s_waitcnt vmcnt(8)" ::: "memory");
        __builtin_amdgcn_s_barrier();
        __builtin_amdgcn_sched_barrier(0);
        COMPUTE_HALF(lds1);
        __builtin_amdgcn_sched_barrier(0);
        EPI_HALF(bj1 * 128 + 64, bmask1, false);
    } else {
        // single strip (g==16, or g==15 && bi>=32): plain, no masks
        asm volatile("s_waitcnt vmcnt(4)" ::: "memory");
        __builtin_amdgcn_s_barrier();
        __builtin_amdgcn_sched_barrier(0);
        COMPUTE_HALF(lds0);
        __builtin_amdgcn_sched_barrier(0);
        EPI_HALF(bj0 * 128, false, false);   // E0 (newer than H1)
        // H1 older than E0: vmcnt(4) retires H1, not E0
        asm volatile("s_waitcnt vmcnt(4)" ::: "memory");
        __builtin_amdgcn_s_barrier();
        __builtin_amdgcn_sched_barrier(0);
        COMPUTE_HALF(lds1);
        __builtin_amdgcn_sched_barrier(0);
        EPI_HALF(bj0 * 128 + 64, false, false);
    }

    // ---- per-row reduction + one atomic per row -------------------------
#pragma unroll
    for (int r = 0; r < 4; ++r) {
        float s = l0[r];
        s += __shfl_xor(s, 1, 64);
        s += __shfl_xor(s, 2, 64);
        s += __shfl_xor(s, 4, 64);
        s += __shfl_xor(s, 8, 64);
        if (m == 0) atomicAdd(&l_arr[i0 + r], s);
    }
#pragma unroll
    for (int r = 0; r < 4; ++r) {
        float s = l1[r];
        s += __shfl_xor(s, 1, 64);
        s += __shfl_xor(s, 2, 64);
        s += __shfl_xor(s, 4, 64);
        s += __shfl_xor(s, 8, 64);
        if (m == 0) atomicAdd(&l_arr[i0 + 16 + r], s);
    }

    // ---- folded final reduce: last block computes the loss --------------
    __threadfence();                         // release our atomics
    if (threadIdx.x == 0)
        last_flag = (atomicAdd(cnt, 1u) == (unsigned)NBLK - 1u) ? 1u : 0u;
    __syncthreads();
    if (last_flag) {
        __threadfence();                     // acquire all blocks' atomics
        float s = 0.f;
#pragma unroll
        for (int k2 = 0; k2 < TWO_B / 256; ++k2) {
            int i = threadIdx.x + k2 * 256;
            float lv = __hip_atomic_load(&l_arr[i], __ATOMIC_RELAXED,
                                         __HIP_MEMORY_SCOPE_AGENT);
            s += FIXED_MAX + LOG2F(lv) * 0.6931471805599453f - picked[i];
        }
#pragma unroll
        for (int off = 32; off >= 1; off >>= 1) s += __shfl_xor(s, off, 64);
        if (lane == 0) fred[w] = s;
        __syncthreads();
        if (threadIdx.x == 0)
            out[0] = (fred[0] + fred[1] + fred[2] + fred[3]) * (1.0f / TWO_B);
    }
}

extern "C" void kernel_launch(void* const* d_in, const int* in_sizes, int n_in,
                              void* d_out, int out_size, void* d_ws, size_t ws_size,
                              hipStream_t stream) {
    const float* emb    = (const float*)d_in[0];
    const int*   labels = (const int*)d_in[1];
    char* ws = (char*)d_ws;
    // ws layout: l_arr[8192] f32 | picked[8192] f32 | cnt (4KB pad) | nb bf16
    float*        l_arr  = (float*)ws;
    float*        picked = (float*)(ws + 32768);
    unsigned int* cnt    = (unsigned int*)(ws + 65536);
    __bf16*       nb     = (__bf16*)(ws + 69632);
    float*        out    = (float*)d_out;

    k_prep<<<TWO_B / 4, 256, 0, stream>>>(emb, labels, nb, picked, l_arr, cnt);
    dim3 g2(64, 17);
    k_gemm<<<g2, 256, 0, stream>>>(nb, l_arr, picked, out, cnt);
}